// Round 2
// baseline (746.082 us; speedup 1.0000x reference)
//
#include <hip/hip_runtime.h>
#include <hip/hip_bf16.h>

// Problem constants (from reference)
#define BB 512
#define NN 1024
#define MM 128
#define OUTD 256
#define MOLD 256
#define IND 512
#define K1 512          // OUTD + MOLD
#define RROWS 65536     // BB * MM
#define BK 64           // k-tile (2 MFMA k-steps per iter)
#define SROW 64         // LDS row stride in shorts (BK)

typedef float f32x4 __attribute__((ext_vector_type(4)));
typedef short s16x8 __attribute__((ext_vector_type(8)));
typedef __bf16 bf16x8 __attribute__((ext_vector_type(8)));

#define AS_GLOBAL const __attribute__((address_space(1))) void
#define AS_LDS __attribute__((address_space(3))) void

__device__ __forceinline__ unsigned short f2bf(float f) {
    unsigned int u = __builtin_bit_cast(unsigned int, f);
    u = (u + 0x7fffu + ((u >> 16) & 1u)) >> 16;
    return (unsigned short)u;
}

// ---------------- prep: W1, W2 fp32 -> bf16 ----------------
__global__ __launch_bounds__(256) void prep_weights(
    const float* __restrict__ W1, const float* __restrict__ W2,
    unsigned short* __restrict__ W1b, unsigned short* __restrict__ W2b) {
    int i = blockIdx.x * 256 + threadIdx.x;  // float4 index, < 65536
    float4 a = ((const float4*)W1)[i];
    ushort4 pa;
    pa.x = f2bf(a.x); pa.y = f2bf(a.y); pa.z = f2bf(a.z); pa.w = f2bf(a.w);
    ((ushort4*)W1b)[i] = pa;
    float4 b = ((const float4*)W2)[i];
    ushort4 pb;
    pb.x = f2bf(b.x); pb.y = f2bf(b.y); pb.z = f2bf(b.z); pb.w = f2bf(b.w);
    ((ushort4*)W2b)[i] = pb;
}

// ---------------- gather: Abuf[b*128+m, :] = bf16(concat(X[b,idx,:], mol[b,:]))
// one wave per output row; fully coalesced (1 KiB load + 0.5 KiB store per half)
__global__ __launch_bounds__(256) void gather_kernel(
    const float* __restrict__ X, const float* __restrict__ mol,
    const int* __restrict__ idxp, unsigned short* __restrict__ Abuf) {
    const int t = threadIdx.x;
    const int lane = t & 63;
    const int row = blockIdx.x * 4 + (t >> 6);   // 0..65535
    const int b = row >> 7, m = row & 127;
    const int idx = idxp[b * MM + m];
    const float4* xr = (const float4*)(X + ((size_t)b * NN + idx) * OUTD);
    const float4* mv = (const float4*)(mol + (size_t)b * MOLD);
    unsigned short* dst = Abuf + (size_t)row * K1;
    float4 v = xr[lane];
    ushort4 p;
    p.x = f2bf(v.x); p.y = f2bf(v.y); p.z = f2bf(v.z); p.w = f2bf(v.w);
    ((ushort4*)dst)[lane] = p;
    v = mv[lane];
    p.x = f2bf(v.x); p.y = f2bf(v.y); p.z = f2bf(v.z); p.w = f2bf(v.w);
    ((ushort4*)(dst + OUTD))[lane] = p;
}

// ---- shared GEMM body pieces ----
// LDS content invariant: seg p (16B) of row r holds global seg p ^ (r&7).
// Staging: chunk c = 1KB = rows c*8..c*8+7; lane covers row c*8+(lane>>3),
// LDS pos lane&7, so it must fetch global seg (lane&7)^(lane>>3).

// ---------------- GEMM1: H = relu(Abuf @ W1b^T + b1) -> bf16 -------------
__global__ __launch_bounds__(256) void gemm1_kernel(
    const unsigned short* __restrict__ Ab, const unsigned short* __restrict__ W1b,
    const float* __restrict__ b1, unsigned short* __restrict__ H) {
    __shared__ __align__(16) unsigned short Asm[128 * SROW];
    __shared__ __align__(16) unsigned short Bsm[128 * SROW];

    const int t = threadIdx.x;
    const int lane = t & 63, w = t >> 6;
    const int row0 = blockIdx.x * 128;
    const int n0 = blockIdx.y * 128;
    const int wr = (w >> 1) * 64, wc = (w & 1) * 64;
    const int lr = lane & 15, quad = lane >> 4;
    const int srow = lane >> 3;                    // row within chunk
    const int sseg = (lane & 7) ^ srow;            // swizzled global seg

    f32x4 acc[4][4];
#pragma unroll
    for (int mi = 0; mi < 4; ++mi)
#pragma unroll
        for (int ni = 0; ni < 4; ++ni) acc[mi][ni] = {0.f, 0.f, 0.f, 0.f};

    for (int ki = 0; ki < K1 / BK; ++ki) {
        const int kt = ki * BK;
#pragma unroll
        for (int j = 0; j < 4; ++j) {
            const int c = j * 4 + w;               // chunk 0..15
            const unsigned short* ga = Ab + (size_t)(row0 + c * 8 + srow) * K1 + kt + sseg * 8;
            __builtin_amdgcn_global_load_lds((AS_GLOBAL*)ga, (AS_LDS*)(Asm + c * 512), 16, 0, 0);
            const unsigned short* gb = W1b + (size_t)(n0 + c * 8 + srow) * K1 + kt + sseg * 8;
            __builtin_amdgcn_global_load_lds((AS_GLOBAL*)gb, (AS_LDS*)(Bsm + c * 512), 16, 0, 0);
        }
        __syncthreads();
#pragma unroll
        for (int h = 0; h < 2; ++h) {
            s16x8 af[4], bfr[4];
#pragma unroll
            for (int i = 0; i < 4; ++i) {
                const int ra = wr + i * 16 + lr;
                af[i] = *(const s16x8*)&Asm[ra * SROW + (((h * 4 + quad) ^ (lr & 7)) * 8)];
                const int rb = wc + i * 16 + lr;
                bfr[i] = *(const s16x8*)&Bsm[rb * SROW + (((h * 4 + quad) ^ (lr & 7)) * 8)];
            }
#pragma unroll
            for (int mi = 0; mi < 4; ++mi)
#pragma unroll
                for (int ni = 0; ni < 4; ++ni)
                    acc[mi][ni] = __builtin_amdgcn_mfma_f32_16x16x32_bf16(
                        __builtin_bit_cast(bf16x8, af[mi]),
                        __builtin_bit_cast(bf16x8, bfr[ni]), acc[mi][ni], 0, 0, 0);
        }
        __syncthreads();
    }

    float bias[4];
#pragma unroll
    for (int ni = 0; ni < 4; ++ni) bias[ni] = b1[n0 + wc + ni * 16 + lr];
#pragma unroll
    for (int mi = 0; mi < 4; ++mi) {
#pragma unroll
        for (int ni = 0; ni < 4; ++ni) {
            const int gcol = n0 + wc + ni * 16 + lr;
#pragma unroll
            for (int rr = 0; rr < 4; ++rr) {
                const int grow = row0 + wr + mi * 16 + quad * 4 + rr;
                float v = acc[mi][ni][rr] + bias[ni];
                v = v > 0.f ? v : 0.f;
                H[(size_t)grow * IND + gcol] = f2bf(v);
            }
        }
    }
}

// ---------------- GEMM2: out = H @ W2b^T + b2 -> fp32 ----------------
__global__ __launch_bounds__(256) void gemm2_kernel(
    const unsigned short* __restrict__ Hb, const unsigned short* __restrict__ W2b,
    const float* __restrict__ b2, float* __restrict__ out) {
    __shared__ __align__(16) unsigned short Asm[128 * SROW];
    __shared__ __align__(16) unsigned short Bsm[128 * SROW];

    const int t = threadIdx.x;
    const int lane = t & 63, w = t >> 6;
    const int row0 = blockIdx.x * 128;
    const int n0 = blockIdx.y * 128;
    const int wr = (w >> 1) * 64, wc = (w & 1) * 64;
    const int lr = lane & 15, quad = lane >> 4;
    const int srow = lane >> 3;
    const int sseg = (lane & 7) ^ srow;

    f32x4 acc[4][4];
#pragma unroll
    for (int mi = 0; mi < 4; ++mi)
#pragma unroll
        for (int ni = 0; ni < 4; ++ni) acc[mi][ni] = {0.f, 0.f, 0.f, 0.f};

    for (int ki = 0; ki < IND / BK; ++ki) {
        const int kt = ki * BK;
#pragma unroll
        for (int j = 0; j < 4; ++j) {
            const int c = j * 4 + w;
            const unsigned short* ga = Hb + (size_t)(row0 + c * 8 + srow) * IND + kt + sseg * 8;
            __builtin_amdgcn_global_load_lds((AS_GLOBAL*)ga, (AS_LDS*)(Asm + c * 512), 16, 0, 0);
            const unsigned short* gb = W2b + (size_t)(n0 + c * 8 + srow) * IND + kt + sseg * 8;
            __builtin_amdgcn_global_load_lds((AS_GLOBAL*)gb, (AS_LDS*)(Bsm + c * 512), 16, 0, 0);
        }
        __syncthreads();
#pragma unroll
        for (int h = 0; h < 2; ++h) {
            s16x8 af[4], bfr[4];
#pragma unroll
            for (int i = 0; i < 4; ++i) {
                const int ra = wr + i * 16 + lr;
                af[i] = *(const s16x8*)&Asm[ra * SROW + (((h * 4 + quad) ^ (lr & 7)) * 8)];
                const int rb = wc + i * 16 + lr;
                bfr[i] = *(const s16x8*)&Bsm[rb * SROW + (((h * 4 + quad) ^ (lr & 7)) * 8)];
            }
#pragma unroll
            for (int mi = 0; mi < 4; ++mi)
#pragma unroll
                for (int ni = 0; ni < 4; ++ni)
                    acc[mi][ni] = __builtin_amdgcn_mfma_f32_16x16x32_bf16(
                        __builtin_bit_cast(bf16x8, af[mi]),
                        __builtin_bit_cast(bf16x8, bfr[ni]), acc[mi][ni], 0, 0, 0);
        }
        __syncthreads();
    }

    float bias[4];
#pragma unroll
    for (int ni = 0; ni < 4; ++ni) bias[ni] = b2[n0 + wc + ni * 16 + lr];
#pragma unroll
    for (int mi = 0; mi < 4; ++mi) {
#pragma unroll
        for (int ni = 0; ni < 4; ++ni) {
            const int gcol = n0 + wc + ni * 16 + lr;
#pragma unroll
            for (int rr = 0; rr < 4; ++rr) {
                const int grow = row0 + wr + mi * 16 + quad * 4 + rr;
                out[(size_t)grow * IND + gcol] = acc[mi][ni][rr] + bias[ni];
            }
        }
    }
}

extern "C" void kernel_launch(void* const* d_in, const int* in_sizes, int n_in,
                              void* d_out, int out_size, void* d_ws, size_t ws_size,
                              hipStream_t stream) {
    const float* X = (const float*)d_in[0];       // [512,1024,256]
    const float* mol = (const float*)d_in[1];     // [512,256]
    const int* idx = (const int*)d_in[2];         // [512,128]
    const float* W1 = (const float*)d_in[3];      // [512,512]
    const float* b1 = (const float*)d_in[4];      // [512]
    const float* W2 = (const float*)d_in[5];      // [512,512]
    const float* b2 = (const float*)d_in[6];      // [512]
    float* out = (float*)d_out;                   // [65536,512]

    // ws: W1b (512KiB) | W2b (512KiB) | Abuf bf16 (64MiB) | H bf16 (64MiB)
    unsigned short* W1b = (unsigned short*)d_ws;
    unsigned short* W2b = W1b + 512 * 512;
    unsigned short* Abuf = W2b + 512 * 512;
    unsigned short* H = Abuf + (size_t)RROWS * K1;

    prep_weights<<<256, 256, 0, stream>>>(W1, W2, W1b, W2b);
    gather_kernel<<<RROWS / 4, 256, 0, stream>>>(X, mol, idx, Abuf);
    gemm1_kernel<<<dim3(RROWS / 128, IND / 128), 256, 0, stream>>>(Abuf, W1b, b1, H);
    gemm2_kernel<<<dim3(RROWS / 128, IND / 128), 256, 0, stream>>>(H, W2b, b2, out);
}